// Round 25
// baseline (285.772 us; speedup 1.0000x reference)
//
#include <hip/hip_runtime.h>

typedef unsigned short u16;
typedef __attribute__((ext_vector_type(8))) short bf16x8;
typedef __attribute__((ext_vector_type(4))) float f32x4;
typedef __attribute__((ext_vector_type(2))) float f32x2;
typedef __attribute__((ext_vector_type(4))) unsigned u32x4;
typedef __attribute__((ext_vector_type(2))) unsigned u32x2;

#define NN    10000
#define EE    160000
#define ET    170000      // EE + NN self loops
#define FIN   2000
#define MPAD  10112       // 79*128
#define K1PAD 2048
#define NH    1280        // heads*channels
#define HEADS 10
#define NT    10          // N tiles (1280/128) == heads
#define NWG2  395         // paired-tile gemm workgroups (each does 2 n-tiles)

__device__ __forceinline__ u16 f32_to_bf16(float f) {
    unsigned u = __float_as_uint(f);
    unsigned r = (u + 0x7fffu + ((u >> 16) & 1u)) >> 16;
    return (u16)r;
}
__device__ __forceinline__ float bf16lo(unsigned pv) { return __uint_as_float(pv << 16); }
__device__ __forceinline__ float bf16hi(unsigned pv) { return __uint_as_float(pv & 0xffff0000u); }

__device__ __forceinline__ void gload16(const u16* g, u16* l) {
    __builtin_amdgcn_global_load_lds(
        (const __attribute__((address_space(1))) void*)g,
        (__attribute__((address_space(3))) void*)l, 16, 0, 0);
}

// ---------------- prep: conv_x + convT(W1) + edge-degree count ----------------
// blocks [0,2048): x f32 -> A1 bf16; [2048,4608): W1 -> B1t; [4608,5273): count
// A1/B1t consumers are cross-XCD (gemm1) -> non-temporal stores keep lines clean.
__global__ __launch_bounds__(256) void k_prep(const float* __restrict__ x,
                                              u32x2* __restrict__ A1,
                                              const float* __restrict__ W1,
                                              u16* __restrict__ B1t,
                                              const int* __restrict__ ei,
                                              int* __restrict__ deg) {
    __shared__ float tile[32][33];
    const int bid = blockIdx.x;
    const int t = threadIdx.x;
    if (bid >= 4608) {                    // fused k_count
        int e = (bid - 4608) * 256 + t;
        if (e < ET) {
            int d = (e < EE) ? ei[EE + e] : (e - EE);
            atomicAdd(&deg[d], 1);
        }
        return;
    }
    if (bid < 2048) {
        const int total = MPAD * (K1PAD / 4);
        for (int idx = bid * 256 + t; idx < total; idx += 2048 * 256) {
            int r = idx >> 9;
            int c = (idx & 511) << 2;
            float4 v = make_float4(0.f, 0.f, 0.f, 0.f);
            if (r < NN && c < FIN) v = *(const float4*)(x + (size_t)r * FIN + c);
            u32x2 p;
            p.x = (unsigned)f32_to_bf16(v.x) | ((unsigned)f32_to_bf16(v.y) << 16);
            p.y = (unsigned)f32_to_bf16(v.z) | ((unsigned)f32_to_bf16(v.w) << 16);
            __builtin_nontemporal_store(p, &A1[idx]);
        }
        return;
    }
    const int tx = t & 31, ty = t >> 5;   // (32, 8)
    int b = bid - 2048;                   // 64 x 40
    int k0 = (b & 63) * 32, n0 = (b >> 6) * 32;
    #pragma unroll
    for (int i = 0; i < 32; i += 8) {
        int k = k0 + ty + i;
        tile[ty + i][tx] = (k < FIN) ? W1[(size_t)k * NH + n0 + tx] : 0.f;
    }
    __syncthreads();
    #pragma unroll
    for (int i = 0; i < 32; i += 8) {
        int n = n0 + ty + i, k = k0 + tx;
        __builtin_nontemporal_store(f32_to_bf16(tile[tx][ty + i]),
                                    &B1t[(size_t)n * K1PAD + k]);
    }
}

// fused: blocks [0,1600) W2->B2t transpose (after gemm1; B2t aliases dead A1);
//        blocks [1600,2265) CSR scatter (after k_scan)
__global__ __launch_bounds__(256) void k_scatW2(const float* __restrict__ W2,
                                                u16* __restrict__ B2t,
                                                const int* __restrict__ ei,
                                                int* __restrict__ cursor,
                                                int* __restrict__ csr_src) {
    __shared__ float tile[32][33];
    const int bid = blockIdx.x;
    const int t = threadIdx.x;
    if (bid >= 1600) {                    // fused k_scatter
        int e = (bid - 1600) * 256 + t;
        if (e < ET) {
            int s = (e < EE) ? ei[e] : (e - EE);
            int d = (e < EE) ? ei[EE + e] : (e - EE);
            int pos = atomicAdd(&cursor[d], 1);
            csr_src[pos] = s;
        }
        return;
    }
    const int tx = t & 31, ty = t >> 5;   // (32, 8)
    int k0 = (bid % 40) * 32, n0 = (bid / 40) * 32;
    #pragma unroll
    for (int i = 0; i < 32; i += 8)
        tile[ty + i][tx] = W2[(size_t)(k0 + ty + i) * NH + n0 + tx];
    __syncthreads();
    #pragma unroll
    for (int i = 0; i < 32; i += 8) {
        int n = n0 + ty + i, k = k0 + tx;
        __builtin_nontemporal_store(f32_to_bf16(tile[tx][ty + i]),
                                    &B2t[(size_t)n * NH + k]);
    }
}

// ---------------- GEMM: paired-tile blocks -> head-major C [10][MPAD][128] ------
// 128x128 tile, BK=64, 8 waves, double-buffered 64KB LDS (round-9/13 schedule).
// Each block computes TWO adjacent-n tiles (same m-panel). K-loop FROZEN.
// C-store non-temporal: H's consumers (attn/agg) are head-pinned = cross-XCD.
__global__ __launch_bounds__(512) void k_gemm(const u16* __restrict__ A,
                                              const u16* __restrict__ Bt,
                                              u16* __restrict__ Chm,
                                              const int Kpad, const int kTiles) {
    __shared__ __attribute__((aligned(16))) u16 S[32768];   // 2 x (A 16KB + B 16KB)
    const int bid = blockIdx.x;
    const int xcd = bid & 7, idx = bid >> 3;
    const int q = NWG2 >> 3, rr = NWG2 & 7;                 // 49, 3
    const int P = (xcd < rr) ? (xcd * (q + 1) + idx)
                             : (rr * (q + 1) + (xcd - rr) * q + idx);
    const int L0 = 2 * P;                                   // pairs never cross m
    const size_t m0 = (size_t)(L0 / NT) * 128;
    const int n0a = (L0 % NT) * 128;

    const int t = threadIdx.x;
    const int lane = t & 63;
    const int wave = t >> 6;              // 0..7
    const int wr = wave >> 2, wc = wave & 3;

    f32x4 acc[4][2] = {};

    const int srow = t >> 3;
    const int klocal = (((t & 7) ^ ((t >> 3) & 7)) << 3);   // elems within BK=64
    const u16* aRow = A + (m0 + srow) * (size_t)Kpad + klocal;
    const u16* bRow = Bt + (size_t)(n0a + srow) * Kpad + klocal;
    const size_t rStep = (size_t)64 * Kpad;
    const size_t bTile = (size_t)128 * Kpad;                // next n-tile offset

#define STAGE(j_, bufb_) do {                                                    \
        char* db = (char*)S + (bufb_) + wave * 1024;                             \
        const int jj_ = (j_) < kTiles ? (j_) : (j_) - kTiles;                    \
        const u16* bR_ = (j_) < kTiles ? bRow : bRow + bTile;                    \
        const u16* aP = aRow + (size_t)jj_ * 64;                                 \
        const u16* bP = bR_ + (size_t)jj_ * 64;                                 \
        gload16(aP,         (u16*)(db));                                         \
        gload16(aP + rStep, (u16*)(db + 8192));                                  \
        gload16(bP,         (u16*)(db + 16384));                                 \
        gload16(bP + rStep, (u16*)(db + 24576));                                 \
    } while (0)

#define EPILOG(ncol_) do {                                                       \
        u16* Cb_ = Chm + (size_t)((ncol_) >> 7) * (MPAD << 7);                   \
        _Pragma("unroll")                                                        \
        for (int mf_ = 0; mf_ < 4; ++mf_)                                        \
            _Pragma("unroll")                                                    \
            for (int i_ = 0; i_ < 4; ++i_) {                                     \
                size_t row_ = m0 + wr * 64 + mf_ * 16 + (lane >> 4) * 4 + i_;    \
                u16* crow_ = Cb_ + row_ * 128 + wc * 32 + (lane & 15);           \
                _Pragma("unroll")                                                \
                for (int nf_ = 0; nf_ < 2; ++nf_)                                \
                    __builtin_nontemporal_store(f32_to_bf16(acc[mf_][nf_][i_]),  \
                                                &crow_[nf_ * 16]);               \
            }                                                                    \
    } while (0)

    STAGE(0, 0);

    const int rl = lane & 15;
    const int kchunk = lane >> 4;                  // 0..3
    const int xorv = (rl & 7) << 4;
    const int aBase0 = (wr * 64 + rl) * 128;       // bytes within A region
    const int bBase0 = (wc * 32 + rl) * 128;       // bytes within B region
    const char* Sb = (const char*)S;
    const int kTotal = 2 * kTiles;

    for (int kt = 0; kt < kTotal; ++kt) {
        asm volatile("s_waitcnt vmcnt(0)" ::: "memory");
        __builtin_amdgcn_s_barrier();
        if (kt + 1 < kTotal) STAGE(kt + 1, ((kt + 1) & 1) * 32768);
        const int bufo = (kt & 1) * 32768;
        #pragma unroll
        for (int ks = 0; ks < 2; ++ks) {
            const int px = (ks * 64 + kchunk * 16) ^ xorv;
            bf16x8 af[4], bfr[2];
            #pragma unroll
            for (int mf = 0; mf < 4; ++mf)
                af[mf] = *(const bf16x8*)(Sb + bufo + aBase0 + mf * 2048 + px);
            #pragma unroll
            for (int nf = 0; nf < 2; ++nf)
                bfr[nf] = *(const bf16x8*)(Sb + bufo + 16384 + bBase0 + nf * 2048 + px);
            #pragma unroll
            for (int mf = 0; mf < 4; ++mf)
                #pragma unroll
                for (int nf = 0; nf < 2; ++nf)
                    acc[mf][nf] = __builtin_amdgcn_mfma_f32_16x16x32_bf16(
                        af[mf], bfr[nf], acc[mf][nf], 0, 0, 0);
        }
        if (kt == kTiles - 1) {            // tile-0 done: store it, reset acc
            EPILOG(n0a);
            #pragma unroll
            for (int mf = 0; mf < 4; ++mf)
                #pragma unroll
                for (int nf = 0; nf < 2; ++nf)
                    acc[mf][nf] = (f32x4){0.f, 0.f, 0.f, 0.f};
        }
    }
    EPILOG(n0a + 128);
#undef STAGE
#undef EPILOG
}

// ---------------- attention coefficients (head-major store: a[h][n]) -----------
__global__ __launch_bounds__(256) void k_attn(const u16* __restrict__ Hhm,
                                              const float* __restrict__ att_s,
                                              const float* __restrict__ att_d,
                                              float* __restrict__ a_src,
                                              float* __restrict__ a_dst) {
    const int lane = threadIdx.x & 63;
    const int n = blockIdx.x * 4 + (threadIdx.x >> 6);
    if (n >= NN) return;
    const unsigned* Hd = (const unsigned*)Hhm;
    #pragma unroll
    for (int h = 0; h < HEADS; ++h) {
        unsigned pv = Hd[((size_t)h * MPAD + n) * 64 + lane];
        float v0 = bf16lo(pv), v1 = bf16hi(pv);
        int c = h * 128 + lane * 2;
        float s = v0 * att_s[c] + v1 * att_s[c + 1];
        float d = v0 * att_d[c] + v1 * att_d[c + 1];
        #pragma unroll
        for (int o = 32; o; o >>= 1) { s += __shfl_xor(s, o); d += __shfl_xor(d, o); }
        if (lane == 0) { a_src[h * NN + n] = s; a_dst[h * NN + n] = d; }
    }
}

// 1024-thread single-block scan: 10 elems/thread
__global__ __launch_bounds__(1024) void k_scan(const int* __restrict__ deg,
                                               int* __restrict__ off,
                                               int* __restrict__ cursor) {
    __shared__ int wt[16];
    const int t = threadIdx.x, lane = t & 63, w = t >> 6;
    const int lo = t * 10;
    const int hi = (lo + 10 < NN) ? lo + 10 : NN;
    int s = 0;
    for (int i = lo; i < hi; ++i) s += deg[i];
    int x = s;
    #pragma unroll
    for (int o = 1; o < 64; o <<= 1) { int y = __shfl_up(x, o); if (lane >= o) x += y; }
    if (lane == 63) wt[w] = x;
    __syncthreads();
    int wp = 0;
    for (int k = 0; k < w; ++k) wp += wt[k];
    int run = wp + x - s;
    for (int i = lo; i < hi; ++i) { off[i] = run; cursor[i] = run; run += deg[i]; }
    if (t == 1023) off[NN] = wp + x;
}

// ---------------- head-split aggregate: wave = (head, 4 nodes), inline softmax ---
// Unroll-4 (proven sweet spot). LAYER 1 stores NODE-MAJOR A2 (consumer gemm2 is
// cross-XCD -> non-temporal); LAYER 2 stores head-major Z (consumer k_final).
template <int LAYER>
__global__ __launch_bounds__(256) void k_agg(const u16* __restrict__ Hhm,
                                             const float* __restrict__ a_src,
                                             const float* __restrict__ a_dst,
                                             const int* __restrict__ off,
                                             const int* __restrict__ csr,
                                             const float* __restrict__ bias,
                                             unsigned* __restrict__ outp) {
    const int bid = blockIdx.x;
    if (LAYER == 1 && bid >= 6256) {     // zero-pad rows NN..MPAD-1 (linear tail)
        int idx = (bid - 6256) * 256 + threadIdx.x;   // 112*640 = 71680 dwords
        if (idx < 112 * 640) outp[(size_t)NN * 640 + idx] = 0u;
        return;
    }
    const int xcd = bid & 7, slot = bid >> 3;
    const int wv = threadIdx.x >> 6, lane = threadIdx.x & 63;
    const int u = slot * 4 + wv;               // [0, 3128)
    if (u >= 3125) return;
    int h, qd;
    if (u < 2500) { h = xcd; qd = u; }
    else {
        int qg = xcd * 625 + (u - 2500);       // [0, 5000)
        h = 8 + (qg >= 2500);
        qd = (qg >= 2500) ? qg - 2500 : qg;
    }
    const int g = lane >> 4, l = lane & 15;
    const int n = qd * 4 + g;
    const int beg = off[n], end = off[n + 1];
    const u16* Hh = Hhm + (size_t)h * (MPAD * 128);
    const float* asl = a_src + (size_t)h * NN;
    const float ad = a_dst[(size_t)h * NN + n];

    float acc[8] = {};
    float den = 0.f;
    int i = beg;
    for (; i + 3 < end; i += 4) {
        const int s0 = csr[i], s1 = csr[i + 1], s2 = csr[i + 2], s3 = csr[i + 3];
        const float a0 = asl[s0], a1 = asl[s1], a2 = asl[s2], a3 = asl[s3];
        const u32x4 v0 = *(const u32x4*)(Hh + (size_t)s0 * 128 + l * 8);
        const u32x4 v1 = *(const u32x4*)(Hh + (size_t)s1 * 128 + l * 8);
        const u32x4 v2 = *(const u32x4*)(Hh + (size_t)s2 * 128 + l * 8);
        const u32x4 v3 = *(const u32x4*)(Hh + (size_t)s3 * 128 + l * 8);
        float e0 = a0 + ad; e0 = (e0 >= 0.f) ? e0 : 0.2f * e0;
        float e1 = a1 + ad; e1 = (e1 >= 0.f) ? e1 : 0.2f * e1;
        float e2 = a2 + ad; e2 = (e2 >= 0.f) ? e2 : 0.2f * e2;
        float e3 = a3 + ad; e3 = (e3 >= 0.f) ? e3 : 0.2f * e3;
        const float w0 = __expf(e0), w1 = __expf(e1);
        const float w2 = __expf(e2), w3 = __expf(e3);
        den += (w0 + w1) + (w2 + w3);
        #pragma unroll
        for (int j = 0; j < 4; ++j) {
            acc[2 * j]     = fmaf(bf16lo(v0[j]), w0, acc[2 * j]);
            acc[2 * j + 1] = fmaf(bf16hi(v0[j]), w0, acc[2 * j + 1]);
            acc[2 * j]     = fmaf(bf16lo(v1[j]), w1, acc[2 * j]);
            acc[2 * j + 1] = fmaf(bf16hi(v1[j]), w1, acc[2 * j + 1]);
            acc[2 * j]     = fmaf(bf16lo(v2[j]), w2, acc[2 * j]);
            acc[2 * j + 1] = fmaf(bf16hi(v2[j]), w2, acc[2 * j + 1]);
            acc[2 * j]     = fmaf(bf16lo(v3[j]), w3, acc[2 * j]);
            acc[2 * j + 1] = fmaf(bf16hi(v3[j]), w3, acc[2 * j + 1]);
        }
    }
    for (; i < end; ++i) {
        const int s0 = csr[i];
        float e0 = asl[s0] + ad; e0 = (e0 >= 0.f) ? e0 : 0.2f * e0;
        const float w0 = __expf(e0);
        const u32x4 v0 = *(const u32x4*)(Hh + (size_t)s0 * 128 + l * 8);
        den += w0;
        #pragma unroll
        for (int j = 0; j < 4; ++j) {
            acc[2 * j]     = fmaf(bf16lo(v0[j]), w0, acc[2 * j]);
            acc[2 * j + 1] = fmaf(bf16hi(v0[j]), w0, acc[2 * j + 1]);
        }
    }
    const float si = 1.f / (den + 1e-16f);

    u32x4 pk;
    if (LAYER == 1) {
        const int c = h * 128 + l * 8;
        #pragma unroll
        for (int j = 0; j < 4; ++j) {
            float v0 = fmaxf(fmaf(acc[2 * j],     si, bias[c + 2 * j]),     0.f);
            float v1 = fmaxf(fmaf(acc[2 * j + 1], si, bias[c + 2 * j + 1]), 0.f);
            pk[j] = (unsigned)f32_to_bf16(v0) | ((unsigned)f32_to_bf16(v1) << 16);
        }
        __builtin_nontemporal_store(pk,
            (u32x4*)(outp + (size_t)n * 640 + h * 64 + l * 4));
    } else {
        #pragma unroll
        for (int j = 0; j < 4; ++j) {
            pk[j] = (unsigned)f32_to_bf16(acc[2 * j] * si)
                  | ((unsigned)f32_to_bf16(acc[2 * j + 1] * si) << 16);
        }
        __builtin_nontemporal_store(pk,
            (u32x4*)(outp + (size_t)h * (MPAD * 64) + (size_t)n * 64 + l * 4));
    }
}

// final: out[n][c] = relu(0.1 * sum_h Z[h][n][c] + b2[c])
__global__ __launch_bounds__(256) void k_final(const unsigned* __restrict__ Z,
                                               const float* __restrict__ b2,
                                               float* __restrict__ out) {
    int t = blockIdx.x * 256 + threadIdx.x;         // NN*64 dword slots
    if (t >= NN * 64) return;
    int n = t >> 6, d = t & 63;
    float s0 = 0.f, s1 = 0.f;
    #pragma unroll
    for (int h = 0; h < HEADS; ++h) {
        unsigned pv = Z[(size_t)h * (MPAD * 64) + (size_t)n * 64 + d];
        s0 += bf16lo(pv);
        s1 += bf16hi(pv);
    }
    f32x2 z;
    z.x = fmaxf(fmaf(s0, 0.1f, b2[2 * d]),     0.f);
    z.y = fmaxf(fmaf(s1, 0.1f, b2[2 * d + 1]), 0.f);
    __builtin_nontemporal_store(z, (f32x2*)(out + (size_t)n * 128 + 2 * d));
}

// ---------------- host ----------------
extern "C" void kernel_launch(void* const* d_in, const int* in_sizes, int n_in,
                              void* d_out, int out_size, void* d_ws, size_t ws_size,
                              hipStream_t stream) {
    const float* x   = (const float*)d_in[0];
    const int*   ei  = (const int*)  d_in[1];
    const float* W1  = (const float*)d_in[2];
    const float* as1 = (const float*)d_in[3];
    const float* ad1 = (const float*)d_in[4];
    const float* b1  = (const float*)d_in[5];
    const float* W2  = (const float*)d_in[6];
    const float* as2 = (const float*)d_in[7];
    const float* ad2 = (const float*)d_in[8];
    const float* b2  = (const float*)d_in[9];

    char* ws = (char*)d_ws;
    const size_t A1_OFF  = 0;                       // A1 [MPAD][2048] bf16 (41.4MB)
    const size_t A2_OFF  = 0;                       // A2 node-major [MPAD][1280] bf16
    const size_t B2T_OFF = (size_t)MPAD * NH * 2;   // aliases dead-A1 tail; write AFTER gemm1
    const size_t H_OFF   = (size_t)MPAD * K1PAD * 2;        // 41,418,752
    const size_t B1T_OFF = H_OFF + (size_t)MPAD * NH * 2;   // 67,305,472
    size_t o = B1T_OFF + (size_t)NH * K1PAD * 2;
    const size_t AS_OFF  = o; o += 400128;
    const size_t AD_OFF  = o; o += 400128;
    const size_t DEG_OFF = o; o += 40064;
    const size_t OFF_OFF = o; o += 40064;
    const size_t CUR_OFF = o; o += 40064;
    const size_t CSR_OFF = o; o += 680064;
    if (ws_size < o) return;

    u16*      A1   = (u16*)(ws + A1_OFF);
    unsigned* A2   = (unsigned*)(ws + A2_OFF);
    u16*      B2t  = (u16*)(ws + B2T_OFF);
    u16*      H    = (u16*)(ws + H_OFF);
    u16*      B1t  = (u16*)(ws + B1T_OFF);
    float*    aS   = (float*)(ws + AS_OFF);
    float*    aD   = (float*)(ws + AD_OFF);
    int*      deg  = (int*)(ws + DEG_OFF);
    int*      offp = (int*)(ws + OFF_OFF);
    int*      cur  = (int*)(ws + CUR_OFF);
    int*      csr  = (int*)(ws + CSR_OFF);

    // prep (x->A1, W1->B1t) + fused edge-degree count
    hipMemsetAsync(deg, 0, NN * sizeof(int), stream);
    k_prep<<<5273, 256, 0, stream>>>(x, (u32x2*)A1, W1, B1t, ei, deg);
    k_scan<<<1, 1024, 0, stream>>>(deg, offp, cur);

    // layer 1
    k_gemm<<<NWG2, 512, 0, stream>>>(A1, B1t, H, K1PAD, K1PAD / 64);
    k_scatW2<<<2265, 256, 0, stream>>>(W2, B2t, ei, cur, csr);  // W2->B2t + scatter
    k_attn<<<2500, 256, 0, stream>>>(H, as1, ad1, aS, aD);
    k_agg<1><<<6536, 256, 0, stream>>>(H, aS, aD, offp, csr, b1, A2);

    // layer 2 (A2 node-major -> same contiguous-K path as gemm1)
    k_gemm<<<NWG2, 512, 0, stream>>>((u16*)A2, B2t, H, NH, NH / 64);
    k_attn<<<2500, 256, 0, stream>>>(H, as2, ad2, aS, aD);
    k_agg<2><<<6256, 256, 0, stream>>>(H, aS, aD, offp, csr, b2, A2);
    k_final<<<(NN * 64 + 255) / 256, 256, 0, stream>>>(A2, b2, (float*)d_out);
}

// Round 26
// 264.710 us; speedup vs baseline: 1.0796x; 1.0796x over previous
//
#include <hip/hip_runtime.h>

typedef unsigned short u16;
typedef __attribute__((ext_vector_type(8))) short bf16x8;
typedef __attribute__((ext_vector_type(4))) float f32x4;
typedef __attribute__((ext_vector_type(4))) unsigned u32x4;

#define NN    10000
#define EE    160000
#define ET    170000      // EE + NN self loops
#define FIN   2000
#define MPAD  10112       // 79*128
#define K1PAD 2048
#define NH    1280        // heads*channels
#define HEADS 10
#define NT    10          // N tiles (1280/128) == heads
#define NWG2  395         // paired-tile gemm workgroups (each does 2 n-tiles)

__device__ __forceinline__ u16 f32_to_bf16(float f) {
    unsigned u = __float_as_uint(f);
    unsigned r = (u + 0x7fffu + ((u >> 16) & 1u)) >> 16;
    return (u16)r;
}
__device__ __forceinline__ float bf16lo(unsigned pv) { return __uint_as_float(pv << 16); }
__device__ __forceinline__ float bf16hi(unsigned pv) { return __uint_as_float(pv & 0xffff0000u); }

__device__ __forceinline__ void gload16(const u16* g, u16* l) {
    __builtin_amdgcn_global_load_lds(
        (const __attribute__((address_space(1))) void*)g,
        (__attribute__((address_space(3))) void*)l, 16, 0, 0);
}

// ---------------- prep: conv_x + convT(W1) + edge-degree count ----------------
// blocks [0,2048): x f32 -> A1 bf16; [2048,4608): W1 -> B1t; [4608,5273): count
__global__ __launch_bounds__(256) void k_prep(const float* __restrict__ x,
                                              uint2* __restrict__ A1,
                                              const float* __restrict__ W1,
                                              u16* __restrict__ B1t,
                                              const int* __restrict__ ei,
                                              int* __restrict__ deg) {
    __shared__ float tile[32][33];
    const int bid = blockIdx.x;
    const int t = threadIdx.x;
    if (bid >= 4608) {                    // fused k_count
        int e = (bid - 4608) * 256 + t;
        if (e < ET) {
            int d = (e < EE) ? ei[EE + e] : (e - EE);
            atomicAdd(&deg[d], 1);
        }
        return;
    }
    if (bid < 2048) {
        const int total = MPAD * (K1PAD / 4);
        for (int idx = bid * 256 + t; idx < total; idx += 2048 * 256) {
            int r = idx >> 9;
            int c = (idx & 511) << 2;
            float4 v = make_float4(0.f, 0.f, 0.f, 0.f);
            if (r < NN && c < FIN) v = *(const float4*)(x + (size_t)r * FIN + c);
            uint2 p;
            p.x = (unsigned)f32_to_bf16(v.x) | ((unsigned)f32_to_bf16(v.y) << 16);
            p.y = (unsigned)f32_to_bf16(v.z) | ((unsigned)f32_to_bf16(v.w) << 16);
            A1[idx] = p;
        }
        return;
    }
    const int tx = t & 31, ty = t >> 5;   // (32, 8)
    int b = bid - 2048;                   // 64 x 40
    int k0 = (b & 63) * 32, n0 = (b >> 6) * 32;
    #pragma unroll
    for (int i = 0; i < 32; i += 8) {
        int k = k0 + ty + i;
        tile[ty + i][tx] = (k < FIN) ? W1[(size_t)k * NH + n0 + tx] : 0.f;
    }
    __syncthreads();
    #pragma unroll
    for (int i = 0; i < 32; i += 8) {
        int n = n0 + ty + i, k = k0 + tx;
        B1t[(size_t)n * K1PAD + k] = f32_to_bf16(tile[tx][ty + i]);
    }
}

// fused: blocks [0,1600) W2->B2t transpose (after gemm1; B2t aliases dead A1);
//        blocks [1600,2265) CSR scatter (after k_scan)
__global__ __launch_bounds__(256) void k_scatW2(const float* __restrict__ W2,
                                                u16* __restrict__ B2t,
                                                const int* __restrict__ ei,
                                                int* __restrict__ cursor,
                                                int* __restrict__ csr_src) {
    __shared__ float tile[32][33];
    const int bid = blockIdx.x;
    const int t = threadIdx.x;
    if (bid >= 1600) {                    // fused k_scatter
        int e = (bid - 1600) * 256 + t;
        if (e < ET) {
            int s = (e < EE) ? ei[e] : (e - EE);
            int d = (e < EE) ? ei[EE + e] : (e - EE);
            int pos = atomicAdd(&cursor[d], 1);
            csr_src[pos] = s;
        }
        return;
    }
    const int tx = t & 31, ty = t >> 5;   // (32, 8)
    int k0 = (bid % 40) * 32, n0 = (bid / 40) * 32;
    #pragma unroll
    for (int i = 0; i < 32; i += 8)
        tile[ty + i][tx] = W2[(size_t)(k0 + ty + i) * NH + n0 + tx];
    __syncthreads();
    #pragma unroll
    for (int i = 0; i < 32; i += 8) {
        int n = n0 + ty + i, k = k0 + tx;
        B2t[(size_t)n * NH + k] = f32_to_bf16(tile[tx][ty + i]);
    }
}

// ---------------- GEMM: paired-tile blocks -> head-major C [10][MPAD][128] ------
// 128x128 tile, BK=64, 8 waves, double-buffered 64KB LDS (round-9/13 schedule).
// Each block computes TWO adjacent-n tiles (same m-panel). FROZEN.
__global__ __launch_bounds__(512) void k_gemm(const u16* __restrict__ A,
                                              const u16* __restrict__ Bt,
                                              u16* __restrict__ Chm,
                                              const int Kpad, const int kTiles) {
    __shared__ __attribute__((aligned(16))) u16 S[32768];   // 2 x (A 16KB + B 16KB)
    const int bid = blockIdx.x;
    const int xcd = bid & 7, idx = bid >> 3;
    const int q = NWG2 >> 3, rr = NWG2 & 7;                 // 49, 3
    const int P = (xcd < rr) ? (xcd * (q + 1) + idx)
                             : (rr * (q + 1) + (xcd - rr) * q + idx);
    const int L0 = 2 * P;                                   // pairs never cross m
    const size_t m0 = (size_t)(L0 / NT) * 128;
    const int n0a = (L0 % NT) * 128;

    const int t = threadIdx.x;
    const int lane = t & 63;
    const int wave = t >> 6;              // 0..7
    const int wr = wave >> 2, wc = wave & 3;

    f32x4 acc[4][2] = {};

    const int srow = t >> 3;
    const int klocal = (((t & 7) ^ ((t >> 3) & 7)) << 3);   // elems within BK=64
    const u16* aRow = A + (m0 + srow) * (size_t)Kpad + klocal;
    const u16* bRow = Bt + (size_t)(n0a + srow) * Kpad + klocal;
    const size_t rStep = (size_t)64 * Kpad;
    const size_t bTile = (size_t)128 * Kpad;                // next n-tile offset

#define STAGE(j_, bufb_) do {                                                    \
        char* db = (char*)S + (bufb_) + wave * 1024;                             \
        const int jj_ = (j_) < kTiles ? (j_) : (j_) - kTiles;                    \
        const u16* bR_ = (j_) < kTiles ? bRow : bRow + bTile;                    \
        const u16* aP = aRow + (size_t)jj_ * 64;                                 \
        const u16* bP = bR_ + (size_t)jj_ * 64;                                 \
        gload16(aP,         (u16*)(db));                                         \
        gload16(aP + rStep, (u16*)(db + 8192));                                  \
        gload16(bP,         (u16*)(db + 16384));                                 \
        gload16(bP + rStep, (u16*)(db + 24576));                                 \
    } while (0)

#define EPILOG(ncol_) do {                                                       \
        u16* Cb_ = Chm + (size_t)((ncol_) >> 7) * (MPAD << 7);                   \
        _Pragma("unroll")                                                        \
        for (int mf_ = 0; mf_ < 4; ++mf_)                                        \
            _Pragma("unroll")                                                    \
            for (int i_ = 0; i_ < 4; ++i_) {                                     \
                size_t row_ = m0 + wr * 64 + mf_ * 16 + (lane >> 4) * 4 + i_;    \
                u16* crow_ = Cb_ + row_ * 128 + wc * 32 + (lane & 15);           \
                _Pragma("unroll")                                                \
                for (int nf_ = 0; nf_ < 2; ++nf_)                                \
                    crow_[nf_ * 16] = f32_to_bf16(acc[mf_][nf_][i_]);            \
            }                                                                    \
    } while (0)

    STAGE(0, 0);

    const int rl = lane & 15;
    const int kchunk = lane >> 4;                  // 0..3
    const int xorv = (rl & 7) << 4;
    const int aBase0 = (wr * 64 + rl) * 128;       // bytes within A region
    const int bBase0 = (wc * 32 + rl) * 128;       // bytes within B region
    const char* Sb = (const char*)S;
    const int kTotal = 2 * kTiles;

    for (int kt = 0; kt < kTotal; ++kt) {
        asm volatile("s_waitcnt vmcnt(0)" ::: "memory");
        __builtin_amdgcn_s_barrier();
        if (kt + 1 < kTotal) STAGE(kt + 1, ((kt + 1) & 1) * 32768);
        const int bufo = (kt & 1) * 32768;
        #pragma unroll
        for (int ks = 0; ks < 2; ++ks) {
            const int px = (ks * 64 + kchunk * 16) ^ xorv;
            bf16x8 af[4], bfr[2];
            #pragma unroll
            for (int mf = 0; mf < 4; ++mf)
                af[mf] = *(const bf16x8*)(Sb + bufo + aBase0 + mf * 2048 + px);
            #pragma unroll
            for (int nf = 0; nf < 2; ++nf)
                bfr[nf] = *(const bf16x8*)(Sb + bufo + 16384 + bBase0 + nf * 2048 + px);
            #pragma unroll
            for (int mf = 0; mf < 4; ++mf)
                #pragma unroll
                for (int nf = 0; nf < 2; ++nf)
                    acc[mf][nf] = __builtin_amdgcn_mfma_f32_16x16x32_bf16(
                        af[mf], bfr[nf], acc[mf][nf], 0, 0, 0);
        }
        if (kt == kTiles - 1) {            // tile-0 done: store it, reset acc
            EPILOG(n0a);
            #pragma unroll
            for (int mf = 0; mf < 4; ++mf)
                #pragma unroll
                for (int nf = 0; nf < 2; ++nf)
                    acc[mf][nf] = (f32x4){0.f, 0.f, 0.f, 0.f};
        }
    }
    EPILOG(n0a + 128);
#undef STAGE
#undef EPILOG
}

// ---------------- attention coefficients (head-major store: a[h][n]) -----------
__global__ __launch_bounds__(256) void k_attn(const u16* __restrict__ Hhm,
                                              const float* __restrict__ att_s,
                                              const float* __restrict__ att_d,
                                              float* __restrict__ a_src,
                                              float* __restrict__ a_dst) {
    const int lane = threadIdx.x & 63;
    const int n = blockIdx.x * 4 + (threadIdx.x >> 6);
    if (n >= NN) return;
    const unsigned* Hd = (const unsigned*)Hhm;
    #pragma unroll
    for (int h = 0; h < HEADS; ++h) {
        unsigned pv = Hd[((size_t)h * MPAD + n) * 64 + lane];
        float v0 = bf16lo(pv), v1 = bf16hi(pv);
        int c = h * 128 + lane * 2;
        float s = v0 * att_s[c] + v1 * att_s[c + 1];
        float d = v0 * att_d[c] + v1 * att_d[c + 1];
        #pragma unroll
        for (int o = 32; o; o >>= 1) { s += __shfl_xor(s, o); d += __shfl_xor(d, o); }
        if (lane == 0) { a_src[h * NN + n] = s; a_dst[h * NN + n] = d; }
    }
}

// 1024-thread single-block scan: 10 elems/thread
__global__ __launch_bounds__(1024) void k_scan(const int* __restrict__ deg,
                                               int* __restrict__ off,
                                               int* __restrict__ cursor) {
    __shared__ int wt[16];
    const int t = threadIdx.x, lane = t & 63, w = t >> 6;
    const int lo = t * 10;
    const int hi = (lo + 10 < NN) ? lo + 10 : NN;
    int s = 0;
    for (int i = lo; i < hi; ++i) s += deg[i];
    int x = s;
    #pragma unroll
    for (int o = 1; o < 64; o <<= 1) { int y = __shfl_up(x, o); if (lane >= o) x += y; }
    if (lane == 63) wt[w] = x;
    __syncthreads();
    int wp = 0;
    for (int k = 0; k < w; ++k) wp += wt[k];
    int run = wp + x - s;
    for (int i = lo; i < hi; ++i) { off[i] = run; cursor[i] = run; run += deg[i]; }
    if (t == 1023) off[NN] = wp + x;
}

// ---------------- head-split aggregate: wave = (head, 4 nodes), inline softmax ---
// Unroll-4 (proven sweet spot). LAYER 1 stores NODE-MAJOR A2; LAYER 2 head-major Z.
template <int LAYER>
__global__ __launch_bounds__(256) void k_agg(const u16* __restrict__ Hhm,
                                             const float* __restrict__ a_src,
                                             const float* __restrict__ a_dst,
                                             const int* __restrict__ off,
                                             const int* __restrict__ csr,
                                             const float* __restrict__ bias,
                                             unsigned* __restrict__ outp) {
    const int bid = blockIdx.x;
    if (LAYER == 1 && bid >= 6256) {     // zero-pad rows NN..MPAD-1 (linear tail)
        int idx = (bid - 6256) * 256 + threadIdx.x;   // 112*640 = 71680 dwords
        if (idx < 112 * 640) outp[(size_t)NN * 640 + idx] = 0u;
        return;
    }
    const int xcd = bid & 7, slot = bid >> 3;
    const int wv = threadIdx.x >> 6, lane = threadIdx.x & 63;
    const int u = slot * 4 + wv;               // [0, 3128)
    if (u >= 3125) return;
    int h, qd;
    if (u < 2500) { h = xcd; qd = u; }
    else {
        int qg = xcd * 625 + (u - 2500);       // [0, 5000)
        h = 8 + (qg >= 2500);
        qd = (qg >= 2500) ? qg - 2500 : qg;
    }
    const int g = lane >> 4, l = lane & 15;
    const int n = qd * 4 + g;
    const int beg = off[n], end = off[n + 1];
    const u16* Hh = Hhm + (size_t)h * (MPAD * 128);
    const float* asl = a_src + (size_t)h * NN;
    const float ad = a_dst[(size_t)h * NN + n];

    float acc[8] = {};
    float den = 0.f;
    int i = beg;
    for (; i + 3 < end; i += 4) {
        const int s0 = csr[i], s1 = csr[i + 1], s2 = csr[i + 2], s3 = csr[i + 3];
        const float a0 = asl[s0], a1 = asl[s1], a2 = asl[s2], a3 = asl[s3];
        const u32x4 v0 = *(const u32x4*)(Hh + (size_t)s0 * 128 + l * 8);
        const u32x4 v1 = *(const u32x4*)(Hh + (size_t)s1 * 128 + l * 8);
        const u32x4 v2 = *(const u32x4*)(Hh + (size_t)s2 * 128 + l * 8);
        const u32x4 v3 = *(const u32x4*)(Hh + (size_t)s3 * 128 + l * 8);
        float e0 = a0 + ad; e0 = (e0 >= 0.f) ? e0 : 0.2f * e0;
        float e1 = a1 + ad; e1 = (e1 >= 0.f) ? e1 : 0.2f * e1;
        float e2 = a2 + ad; e2 = (e2 >= 0.f) ? e2 : 0.2f * e2;
        float e3 = a3 + ad; e3 = (e3 >= 0.f) ? e3 : 0.2f * e3;
        const float w0 = __expf(e0), w1 = __expf(e1);
        const float w2 = __expf(e2), w3 = __expf(e3);
        den += (w0 + w1) + (w2 + w3);
        #pragma unroll
        for (int j = 0; j < 4; ++j) {
            acc[2 * j]     = fmaf(bf16lo(v0[j]), w0, acc[2 * j]);
            acc[2 * j + 1] = fmaf(bf16hi(v0[j]), w0, acc[2 * j + 1]);
            acc[2 * j]     = fmaf(bf16lo(v1[j]), w1, acc[2 * j]);
            acc[2 * j + 1] = fmaf(bf16hi(v1[j]), w1, acc[2 * j + 1]);
            acc[2 * j]     = fmaf(bf16lo(v2[j]), w2, acc[2 * j]);
            acc[2 * j + 1] = fmaf(bf16hi(v2[j]), w2, acc[2 * j + 1]);
            acc[2 * j]     = fmaf(bf16lo(v3[j]), w3, acc[2 * j]);
            acc[2 * j + 1] = fmaf(bf16hi(v3[j]), w3, acc[2 * j + 1]);
        }
    }
    for (; i < end; ++i) {
        const int s0 = csr[i];
        float e0 = asl[s0] + ad; e0 = (e0 >= 0.f) ? e0 : 0.2f * e0;
        const float w0 = __expf(e0);
        const u32x4 v0 = *(const u32x4*)(Hh + (size_t)s0 * 128 + l * 8);
        den += w0;
        #pragma unroll
        for (int j = 0; j < 4; ++j) {
            acc[2 * j]     = fmaf(bf16lo(v0[j]), w0, acc[2 * j]);
            acc[2 * j + 1] = fmaf(bf16hi(v0[j]), w0, acc[2 * j + 1]);
        }
    }
    const float si = 1.f / (den + 1e-16f);

    u32x4 pk;
    if (LAYER == 1) {
        const int c = h * 128 + l * 8;
        #pragma unroll
        for (int j = 0; j < 4; ++j) {
            float v0 = fmaxf(fmaf(acc[2 * j],     si, bias[c + 2 * j]),     0.f);
            float v1 = fmaxf(fmaf(acc[2 * j + 1], si, bias[c + 2 * j + 1]), 0.f);
            pk[j] = (unsigned)f32_to_bf16(v0) | ((unsigned)f32_to_bf16(v1) << 16);
        }
        *(u32x4*)(outp + (size_t)n * 640 + h * 64 + l * 4) = pk;
    } else {
        #pragma unroll
        for (int j = 0; j < 4; ++j) {
            pk[j] = (unsigned)f32_to_bf16(acc[2 * j] * si)
                  | ((unsigned)f32_to_bf16(acc[2 * j + 1] * si) << 16);
        }
        *(u32x4*)(outp + (size_t)h * (MPAD * 64) + (size_t)n * 64 + l * 4) = pk;
    }
}

// final: out[n][c] = relu(0.1 * sum_h Z[h][n][c] + b2[c])
__global__ __launch_bounds__(256) void k_final(const unsigned* __restrict__ Z,
                                               const float* __restrict__ b2,
                                               float* __restrict__ out) {
    int t = blockIdx.x * 256 + threadIdx.x;         // NN*64 dword slots
    if (t >= NN * 64) return;
    int n = t >> 6, d = t & 63;
    float s0 = 0.f, s1 = 0.f;
    #pragma unroll
    for (int h = 0; h < HEADS; ++h) {
        unsigned pv = Z[(size_t)h * (MPAD * 64) + (size_t)n * 64 + d];
        s0 += bf16lo(pv);
        s1 += bf16hi(pv);
    }
    float2 z;
    z.x = fmaxf(fmaf(s0, 0.1f, b2[2 * d]),     0.f);
    z.y = fmaxf(fmaf(s1, 0.1f, b2[2 * d + 1]), 0.f);
    *(float2*)(out + (size_t)n * 128 + 2 * d) = z;
}

// ---------------- host ----------------
extern "C" void kernel_launch(void* const* d_in, const int* in_sizes, int n_in,
                              void* d_out, int out_size, void* d_ws, size_t ws_size,
                              hipStream_t stream) {
    const float* x   = (const float*)d_in[0];
    const int*   ei  = (const int*)  d_in[1];
    const float* W1  = (const float*)d_in[2];
    const float* as1 = (const float*)d_in[3];
    const float* ad1 = (const float*)d_in[4];
    const float* b1  = (const float*)d_in[5];
    const float* W2  = (const float*)d_in[6];
    const float* as2 = (const float*)d_in[7];
    const float* ad2 = (const float*)d_in[8];
    const float* b2  = (const float*)d_in[9];

    char* ws = (char*)d_ws;
    const size_t A1_OFF  = 0;                       // A1 [MPAD][2048] bf16 (41.4MB)
    const size_t A2_OFF  = 0;                       // A2 node-major [MPAD][1280] bf16
    const size_t B2T_OFF = (size_t)MPAD * NH * 2;   // aliases dead-A1 tail; write AFTER gemm1
    const size_t H_OFF   = (size_t)MPAD * K1PAD * 2;        // 41,418,752
    const size_t B1T_OFF = H_OFF + (size_t)MPAD * NH * 2;   // 67,305,472
    size_t o = B1T_OFF + (size_t)NH * K1PAD * 2;
    const size_t AS_OFF  = o; o += 400128;
    const size_t AD_OFF  = o; o += 400128;
    const size_t DEG_OFF = o; o += 40064;
    const size_t OFF_OFF = o; o += 40064;
    const size_t CUR_OFF = o; o += 40064;
    const size_t CSR_OFF = o; o += 680064;
    if (ws_size < o) return;

    u16*      A1   = (u16*)(ws + A1_OFF);
    unsigned* A2   = (unsigned*)(ws + A2_OFF);
    u16*      B2t  = (u16*)(ws + B2T_OFF);
    u16*      H    = (u16*)(ws + H_OFF);
    u16*      B1t  = (u16*)(ws + B1T_OFF);
    float*    aS   = (float*)(ws + AS_OFF);
    float*    aD   = (float*)(ws + AD_OFF);
    int*      deg  = (int*)(ws + DEG_OFF);
    int*      offp = (int*)(ws + OFF_OFF);
    int*      cur  = (int*)(ws + CUR_OFF);
    int*      csr  = (int*)(ws + CSR_OFF);

    // prep (x->A1, W1->B1t) + fused edge-degree count
    hipMemsetAsync(deg, 0, NN * sizeof(int), stream);
    k_prep<<<5273, 256, 0, stream>>>(x, (uint2*)A1, W1, B1t, ei, deg);
    k_scan<<<1, 1024, 0, stream>>>(deg, offp, cur);

    // layer 1
    k_gemm<<<NWG2, 512, 0, stream>>>(A1, B1t, H, K1PAD, K1PAD / 64);
    k_scatW2<<<2265, 256, 0, stream>>>(W2, B2t, ei, cur, csr);  // W2->B2t + scatter
    k_attn<<<2500, 256, 0, stream>>>(H, as1, ad1, aS, aD);
    k_agg<1><<<6536, 256, 0, stream>>>(H, aS, aD, offp, csr, b1, A2);

    // layer 2 (A2 node-major -> same contiguous-K path as gemm1)
    k_gemm<<<NWG2, 512, 0, stream>>>((u16*)A2, B2t, H, NH, NH / 64);
    k_attn<<<2500, 256, 0, stream>>>(H, as2, ad2, aS, aD);
    k_agg<2><<<6256, 256, 0, stream>>>(H, aS, aD, offp, csr, b2, A2);
    k_final<<<(NN * 64 + 255) / 256, 256, 0, stream>>>(A2, b2, (float*)d_out);
}

// Round 27
// 261.195 us; speedup vs baseline: 1.0941x; 1.0135x over previous
//
#include <hip/hip_runtime.h>

typedef unsigned short u16;
typedef __attribute__((ext_vector_type(8))) short bf16x8;
typedef __attribute__((ext_vector_type(4))) float f32x4;
typedef __attribute__((ext_vector_type(4))) unsigned u32x4;

#define NN    10000
#define EE    160000
#define ET    170000      // EE + NN self loops
#define FIN   2000
#define MPAD  10112       // 79*128
#define K1PAD 2048
#define NH    1280        // heads*channels
#define HEADS 10
#define NT    10          // N tiles (1280/128) == heads
#define NWG2  395         // paired-tile gemm workgroups (each does 2 n-tiles)

__device__ __forceinline__ u16 f32_to_bf16(float f) {
    unsigned u = __float_as_uint(f);
    unsigned r = (u + 0x7fffu + ((u >> 16) & 1u)) >> 16;
    return (u16)r;
}
__device__ __forceinline__ float bf16lo(unsigned pv) { return __uint_as_float(pv << 16); }
__device__ __forceinline__ float bf16hi(unsigned pv) { return __uint_as_float(pv & 0xffff0000u); }

__device__ __forceinline__ void gload16(const u16* g, u16* l) {
    __builtin_amdgcn_global_load_lds(
        (const __attribute__((address_space(1))) void*)g,
        (__attribute__((address_space(3))) void*)l, 16, 0, 0);
}

// ---------------- prep: conv_x + convT(W1) + edge-degree count ----------------
// blocks [0,2048): x f32 -> A1 bf16; [2048,4608): W1 -> B1t; [4608,5273): count
__global__ __launch_bounds__(256) void k_prep(const float* __restrict__ x,
                                              uint2* __restrict__ A1,
                                              const float* __restrict__ W1,
                                              u16* __restrict__ B1t,
                                              const int* __restrict__ ei,
                                              int* __restrict__ deg) {
    __shared__ float tile[32][33];
    const int bid = blockIdx.x;
    const int t = threadIdx.x;
    if (bid >= 4608) {                    // fused k_count
        int e = (bid - 4608) * 256 + t;
        if (e < ET) {
            int d = (e < EE) ? ei[EE + e] : (e - EE);
            atomicAdd(&deg[d], 1);
        }
        return;
    }
    if (bid < 2048) {
        const int total = MPAD * (K1PAD / 4);
        for (int idx = bid * 256 + t; idx < total; idx += 2048 * 256) {
            int r = idx >> 9;
            int c = (idx & 511) << 2;
            float4 v = make_float4(0.f, 0.f, 0.f, 0.f);
            if (r < NN && c < FIN) v = *(const float4*)(x + (size_t)r * FIN + c);
            uint2 p;
            p.x = (unsigned)f32_to_bf16(v.x) | ((unsigned)f32_to_bf16(v.y) << 16);
            p.y = (unsigned)f32_to_bf16(v.z) | ((unsigned)f32_to_bf16(v.w) << 16);
            A1[idx] = p;
        }
        return;
    }
    const int tx = t & 31, ty = t >> 5;   // (32, 8)
    int b = bid - 2048;                   // 64 x 40
    int k0 = (b & 63) * 32, n0 = (b >> 6) * 32;
    #pragma unroll
    for (int i = 0; i < 32; i += 8) {
        int k = k0 + ty + i;
        tile[ty + i][tx] = (k < FIN) ? W1[(size_t)k * NH + n0 + tx] : 0.f;
    }
    __syncthreads();
    #pragma unroll
    for (int i = 0; i < 32; i += 8) {
        int n = n0 + ty + i, k = k0 + tx;
        B1t[(size_t)n * K1PAD + k] = f32_to_bf16(tile[tx][ty + i]);
    }
}

// fused post-gemm1 kernel:
//   blocks [0,1600): W2 -> B2t transpose (B2t aliases dead A1 tail)
//   blocks [1600,2265): CSR scatter (after k_scan)
//   blocks [2265,4765): layer-1 attention coefficients (reads H)
__global__ __launch_bounds__(256) void k_scatW2(const float* __restrict__ W2,
                                                u16* __restrict__ B2t,
                                                const int* __restrict__ ei,
                                                int* __restrict__ cursor,
                                                int* __restrict__ csr_src,
                                                const u16* __restrict__ Hhm,
                                                const float* __restrict__ att_s,
                                                const float* __restrict__ att_d,
                                                float* __restrict__ a_src,
                                                float* __restrict__ a_dst) {
    __shared__ float tile[32][33];
    const int bid = blockIdx.x;
    const int t = threadIdx.x;
    if (bid >= 2265) {                    // fused layer-1 k_attn
        const int lane = t & 63;
        const int n = (bid - 2265) * 4 + (t >> 6);
        if (n >= NN) return;
        const unsigned* Hd = (const unsigned*)Hhm;
        #pragma unroll
        for (int h = 0; h < HEADS; ++h) {
            unsigned pv = Hd[((size_t)h * MPAD + n) * 64 + lane];
            float v0 = bf16lo(pv), v1 = bf16hi(pv);
            int c = h * 128 + lane * 2;
            float s = v0 * att_s[c] + v1 * att_s[c + 1];
            float d = v0 * att_d[c] + v1 * att_d[c + 1];
            #pragma unroll
            for (int o = 32; o; o >>= 1) { s += __shfl_xor(s, o); d += __shfl_xor(d, o); }
            if (lane == 0) { a_src[h * NN + n] = s; a_dst[h * NN + n] = d; }
        }
        return;
    }
    if (bid >= 1600) {                    // fused k_scatter
        int e = (bid - 1600) * 256 + t;
        if (e < ET) {
            int s = (e < EE) ? ei[e] : (e - EE);
            int d = (e < EE) ? ei[EE + e] : (e - EE);
            int pos = atomicAdd(&cursor[d], 1);
            csr_src[pos] = s;
        }
        return;
    }
    const int tx = t & 31, ty = t >> 5;   // (32, 8)
    int k0 = (bid % 40) * 32, n0 = (bid / 40) * 32;
    #pragma unroll
    for (int i = 0; i < 32; i += 8)
        tile[ty + i][tx] = W2[(size_t)(k0 + ty + i) * NH + n0 + tx];
    __syncthreads();
    #pragma unroll
    for (int i = 0; i < 32; i += 8) {
        int n = n0 + ty + i, k = k0 + tx;
        B2t[(size_t)n * NH + k] = f32_to_bf16(tile[tx][ty + i]);
    }
}

// ---------------- GEMM: paired-tile blocks -> head-major C [10][MPAD][128] ------
// 128x128 tile, BK=64, 8 waves, double-buffered 64KB LDS (round-9/13 schedule).
// Each block computes TWO adjacent-n tiles (same m-panel). FROZEN.
__global__ __launch_bounds__(512) void k_gemm(const u16* __restrict__ A,
                                              const u16* __restrict__ Bt,
                                              u16* __restrict__ Chm,
                                              const int Kpad, const int kTiles) {
    __shared__ __attribute__((aligned(16))) u16 S[32768];   // 2 x (A 16KB + B 16KB)
    const int bid = blockIdx.x;
    const int xcd = bid & 7, idx = bid >> 3;
    const int q = NWG2 >> 3, rr = NWG2 & 7;                 // 49, 3
    const int P = (xcd < rr) ? (xcd * (q + 1) + idx)
                             : (rr * (q + 1) + (xcd - rr) * q + idx);
    const int L0 = 2 * P;                                   // pairs never cross m
    const size_t m0 = (size_t)(L0 / NT) * 128;
    const int n0a = (L0 % NT) * 128;

    const int t = threadIdx.x;
    const int lane = t & 63;
    const int wave = t >> 6;              // 0..7
    const int wr = wave >> 2, wc = wave & 3;

    f32x4 acc[4][2] = {};

    const int srow = t >> 3;
    const int klocal = (((t & 7) ^ ((t >> 3) & 7)) << 3);   // elems within BK=64
    const u16* aRow = A + (m0 + srow) * (size_t)Kpad + klocal;
    const u16* bRow = Bt + (size_t)(n0a + srow) * Kpad + klocal;
    const size_t rStep = (size_t)64 * Kpad;
    const size_t bTile = (size_t)128 * Kpad;                // next n-tile offset

#define STAGE(j_, bufb_) do {                                                    \
        char* db = (char*)S + (bufb_) + wave * 1024;                             \
        const int jj_ = (j_) < kTiles ? (j_) : (j_) - kTiles;                    \
        const u16* bR_ = (j_) < kTiles ? bRow : bRow + bTile;                    \
        const u16* aP = aRow + (size_t)jj_ * 64;                                 \
        const u16* bP = bR_ + (size_t)jj_ * 64;                                 \
        gload16(aP,         (u16*)(db));                                         \
        gload16(aP + rStep, (u16*)(db + 8192));                                  \
        gload16(bP,         (u16*)(db + 16384));                                 \
        gload16(bP + rStep, (u16*)(db + 24576));                                 \
    } while (0)

#define EPILOG(ncol_) do {                                                       \
        u16* Cb_ = Chm + (size_t)((ncol_) >> 7) * (MPAD << 7);                   \
        _Pragma("unroll")                                                        \
        for (int mf_ = 0; mf_ < 4; ++mf_)                                        \
            _Pragma("unroll")                                                    \
            for (int i_ = 0; i_ < 4; ++i_) {                                     \
                size_t row_ = m0 + wr * 64 + mf_ * 16 + (lane >> 4) * 4 + i_;    \
                u16* crow_ = Cb_ + row_ * 128 + wc * 32 + (lane & 15);           \
                _Pragma("unroll")                                                \
                for (int nf_ = 0; nf_ < 2; ++nf_)                                \
                    crow_[nf_ * 16] = f32_to_bf16(acc[mf_][nf_][i_]);            \
            }                                                                    \
    } while (0)

    STAGE(0, 0);

    const int rl = lane & 15;
    const int kchunk = lane >> 4;                  // 0..3
    const int xorv = (rl & 7) << 4;
    const int aBase0 = (wr * 64 + rl) * 128;       // bytes within A region
    const int bBase0 = (wc * 32 + rl) * 128;       // bytes within B region
    const char* Sb = (const char*)S;
    const int kTotal = 2 * kTiles;

    for (int kt = 0; kt < kTotal; ++kt) {
        asm volatile("s_waitcnt vmcnt(0)" ::: "memory");
        __builtin_amdgcn_s_barrier();
        if (kt + 1 < kTotal) STAGE(kt + 1, ((kt + 1) & 1) * 32768);
        const int bufo = (kt & 1) * 32768;
        #pragma unroll
        for (int ks = 0; ks < 2; ++ks) {
            const int px = (ks * 64 + kchunk * 16) ^ xorv;
            bf16x8 af[4], bfr[2];
            #pragma unroll
            for (int mf = 0; mf < 4; ++mf)
                af[mf] = *(const bf16x8*)(Sb + bufo + aBase0 + mf * 2048 + px);
            #pragma unroll
            for (int nf = 0; nf < 2; ++nf)
                bfr[nf] = *(const bf16x8*)(Sb + bufo + 16384 + bBase0 + nf * 2048 + px);
            #pragma unroll
            for (int mf = 0; mf < 4; ++mf)
                #pragma unroll
                for (int nf = 0; nf < 2; ++nf)
                    acc[mf][nf] = __builtin_amdgcn_mfma_f32_16x16x32_bf16(
                        af[mf], bfr[nf], acc[mf][nf], 0, 0, 0);
        }
        if (kt == kTiles - 1) {            // tile-0 done: store it, reset acc
            EPILOG(n0a);
            #pragma unroll
            for (int mf = 0; mf < 4; ++mf)
                #pragma unroll
                for (int nf = 0; nf < 2; ++nf)
                    acc[mf][nf] = (f32x4){0.f, 0.f, 0.f, 0.f};
        }
    }
    EPILOG(n0a + 128);
#undef STAGE
#undef EPILOG
}

// ---------------- attention coefficients (layer 2; head-major store a[h][n]) ----
__global__ __launch_bounds__(256) void k_attn(const u16* __restrict__ Hhm,
                                              const float* __restrict__ att_s,
                                              const float* __restrict__ att_d,
                                              float* __restrict__ a_src,
                                              float* __restrict__ a_dst) {
    const int lane = threadIdx.x & 63;
    const int n = blockIdx.x * 4 + (threadIdx.x >> 6);
    if (n >= NN) return;
    const unsigned* Hd = (const unsigned*)Hhm;
    #pragma unroll
    for (int h = 0; h < HEADS; ++h) {
        unsigned pv = Hd[((size_t)h * MPAD + n) * 64 + lane];
        float v0 = bf16lo(pv), v1 = bf16hi(pv);
        int c = h * 128 + lane * 2;
        float s = v0 * att_s[c] + v1 * att_s[c + 1];
        float d = v0 * att_d[c] + v1 * att_d[c + 1];
        #pragma unroll
        for (int o = 32; o; o >>= 1) { s += __shfl_xor(s, o); d += __shfl_xor(d, o); }
        if (lane == 0) { a_src[h * NN + n] = s; a_dst[h * NN + n] = d; }
    }
}

// 1024-thread single-block scan: 10 elems/thread
__global__ __launch_bounds__(1024) void k_scan(const int* __restrict__ deg,
                                               int* __restrict__ off,
                                               int* __restrict__ cursor) {
    __shared__ int wt[16];
    const int t = threadIdx.x, lane = t & 63, w = t >> 6;
    const int lo = t * 10;
    const int hi = (lo + 10 < NN) ? lo + 10 : NN;
    int s = 0;
    for (int i = lo; i < hi; ++i) s += deg[i];
    int x = s;
    #pragma unroll
    for (int o = 1; o < 64; o <<= 1) { int y = __shfl_up(x, o); if (lane >= o) x += y; }
    if (lane == 63) wt[w] = x;
    __syncthreads();
    int wp = 0;
    for (int k = 0; k < w; ++k) wp += wt[k];
    int run = wp + x - s;
    for (int i = lo; i < hi; ++i) { off[i] = run; cursor[i] = run; run += deg[i]; }
    if (t == 1023) off[NN] = wp + x;
}

// ---------------- head-split aggregate: wave = (head, 4 nodes), inline softmax ---
// Unroll-4 (proven sweet spot). LAYER 1 stores NODE-MAJOR A2; LAYER 2 head-major Z.
template <int LAYER>
__global__ __launch_bounds__(256) void k_agg(const u16* __restrict__ Hhm,
                                             const float* __restrict__ a_src,
                                             const float* __restrict__ a_dst,
                                             const int* __restrict__ off,
                                             const int* __restrict__ csr,
                                             const float* __restrict__ bias,
                                             unsigned* __restrict__ outp) {
    const int bid = blockIdx.x;
    if (LAYER == 1 && bid >= 6256) {     // zero-pad rows NN..MPAD-1 (linear tail)
        int idx = (bid - 6256) * 256 + threadIdx.x;   // 112*640 = 71680 dwords
        if (idx < 112 * 640) outp[(size_t)NN * 640 + idx] = 0u;
        return;
    }
    const int xcd = bid & 7, slot = bid >> 3;
    const int wv = threadIdx.x >> 6, lane = threadIdx.x & 63;
    const int u = slot * 4 + wv;               // [0, 3128)
    if (u >= 3125) return;
    int h, qd;
    if (u < 2500) { h = xcd; qd = u; }
    else {
        int qg = xcd * 625 + (u - 2500);       // [0, 5000)
        h = 8 + (qg >= 2500);
        qd = (qg >= 2500) ? qg - 2500 : qg;
    }
    const int g = lane >> 4, l = lane & 15;
    const int n = qd * 4 + g;
    const int beg = off[n], end = off[n + 1];
    const u16* Hh = Hhm + (size_t)h * (MPAD * 128);
    const float* asl = a_src + (size_t)h * NN;
    const float ad = a_dst[(size_t)h * NN + n];

    float acc[8] = {};
    float den = 0.f;
    int i = beg;
    for (; i + 3 < end; i += 4) {
        const int s0 = csr[i], s1 = csr[i + 1], s2 = csr[i + 2], s3 = csr[i + 3];
        const float a0 = asl[s0], a1 = asl[s1], a2 = asl[s2], a3 = asl[s3];
        const u32x4 v0 = *(const u32x4*)(Hh + (size_t)s0 * 128 + l * 8);
        const u32x4 v1 = *(const u32x4*)(Hh + (size_t)s1 * 128 + l * 8);
        const u32x4 v2 = *(const u32x4*)(Hh + (size_t)s2 * 128 + l * 8);
        const u32x4 v3 = *(const u32x4*)(Hh + (size_t)s3 * 128 + l * 8);
        float e0 = a0 + ad; e0 = (e0 >= 0.f) ? e0 : 0.2f * e0;
        float e1 = a1 + ad; e1 = (e1 >= 0.f) ? e1 : 0.2f * e1;
        float e2 = a2 + ad; e2 = (e2 >= 0.f) ? e2 : 0.2f * e2;
        float e3 = a3 + ad; e3 = (e3 >= 0.f) ? e3 : 0.2f * e3;
        const float w0 = __expf(e0), w1 = __expf(e1);
        const float w2 = __expf(e2), w3 = __expf(e3);
        den += (w0 + w1) + (w2 + w3);
        #pragma unroll
        for (int j = 0; j < 4; ++j) {
            acc[2 * j]     = fmaf(bf16lo(v0[j]), w0, acc[2 * j]);
            acc[2 * j + 1] = fmaf(bf16hi(v0[j]), w0, acc[2 * j + 1]);
            acc[2 * j]     = fmaf(bf16lo(v1[j]), w1, acc[2 * j]);
            acc[2 * j + 1] = fmaf(bf16hi(v1[j]), w1, acc[2 * j + 1]);
            acc[2 * j]     = fmaf(bf16lo(v2[j]), w2, acc[2 * j]);
            acc[2 * j + 1] = fmaf(bf16hi(v2[j]), w2, acc[2 * j + 1]);
            acc[2 * j]     = fmaf(bf16lo(v3[j]), w3, acc[2 * j]);
            acc[2 * j + 1] = fmaf(bf16hi(v3[j]), w3, acc[2 * j + 1]);
        }
    }
    for (; i < end; ++i) {
        const int s0 = csr[i];
        float e0 = asl[s0] + ad; e0 = (e0 >= 0.f) ? e0 : 0.2f * e0;
        const float w0 = __expf(e0);
        const u32x4 v0 = *(const u32x4*)(Hh + (size_t)s0 * 128 + l * 8);
        den += w0;
        #pragma unroll
        for (int j = 0; j < 4; ++j) {
            acc[2 * j]     = fmaf(bf16lo(v0[j]), w0, acc[2 * j]);
            acc[2 * j + 1] = fmaf(bf16hi(v0[j]), w0, acc[2 * j + 1]);
        }
    }
    const float si = 1.f / (den + 1e-16f);

    u32x4 pk;
    if (LAYER == 1) {
        const int c = h * 128 + l * 8;
        #pragma unroll
        for (int j = 0; j < 4; ++j) {
            float v0 = fmaxf(fmaf(acc[2 * j],     si, bias[c + 2 * j]),     0.f);
            float v1 = fmaxf(fmaf(acc[2 * j + 1], si, bias[c + 2 * j + 1]), 0.f);
            pk[j] = (unsigned)f32_to_bf16(v0) | ((unsigned)f32_to_bf16(v1) << 16);
        }
        *(u32x4*)(outp + (size_t)n * 640 + h * 64 + l * 4) = pk;
    } else {
        #pragma unroll
        for (int j = 0; j < 4; ++j) {
            pk[j] = (unsigned)f32_to_bf16(acc[2 * j] * si)
                  | ((unsigned)f32_to_bf16(acc[2 * j + 1] * si) << 16);
        }
        *(u32x4*)(outp + (size_t)h * (MPAD * 64) + (size_t)n * 64 + l * 4) = pk;
    }
}

// final: out[n][c] = relu(0.1 * sum_h Z[h][n][c] + b2[c])
__global__ __launch_bounds__(256) void k_final(const unsigned* __restrict__ Z,
                                               const float* __restrict__ b2,
                                               float* __restrict__ out) {
    int t = blockIdx.x * 256 + threadIdx.x;         // NN*64 dword slots
    if (t >= NN * 64) return;
    int n = t >> 6, d = t & 63;
    float s0 = 0.f, s1 = 0.f;
    #pragma unroll
    for (int h = 0; h < HEADS; ++h) {
        unsigned pv = Z[(size_t)h * (MPAD * 64) + (size_t)n * 64 + d];
        s0 += bf16lo(pv);
        s1 += bf16hi(pv);
    }
    float2 z;
    z.x = fmaxf(fmaf(s0, 0.1f, b2[2 * d]),     0.f);
    z.y = fmaxf(fmaf(s1, 0.1f, b2[2 * d + 1]), 0.f);
    *(float2*)(out + (size_t)n * 128 + 2 * d) = z;
}

// ---------------- host ----------------
extern "C" void kernel_launch(void* const* d_in, const int* in_sizes, int n_in,
                              void* d_out, int out_size, void* d_ws, size_t ws_size,
                              hipStream_t stream) {
    const float* x   = (const float*)d_in[0];
    const int*   ei  = (const int*)  d_in[1];
    const float* W1  = (const float*)d_in[2];
    const float* as1 = (const float*)d_in[3];
    const float* ad1 = (const float*)d_in[4];
    const float* b1  = (const float*)d_in[5];
    const float* W2  = (const float*)d_in[6];
    const float* as2 = (const float*)d_in[7];
    const float* ad2 = (const float*)d_in[8];
    const float* b2  = (const float*)d_in[9];

    char* ws = (char*)d_ws;
    const size_t A1_OFF  = 0;                       // A1 [MPAD][2048] bf16 (41.4MB)
    const size_t A2_OFF  = 0;                       // A2 node-major [MPAD][1280] bf16
    const size_t B2T_OFF = (size_t)MPAD * NH * 2;   // aliases dead-A1 tail; write AFTER gemm1
    const size_t H_OFF   = (size_t)MPAD * K1PAD * 2;        // 41,418,752
    const size_t B1T_OFF = H_OFF + (size_t)MPAD * NH * 2;   // 67,305,472
    size_t o = B1T_OFF + (size_t)NH * K1PAD * 2;
    const size_t AS_OFF  = o; o += 400128;
    const size_t AD_OFF  = o; o += 400128;
    const size_t DEG_OFF = o; o += 40064;
    const size_t OFF_OFF = o; o += 40064;
    const size_t CUR_OFF = o; o += 40064;
    const size_t CSR_OFF = o; o += 680064;
    if (ws_size < o) return;

    u16*      A1   = (u16*)(ws + A1_OFF);
    unsigned* A2   = (unsigned*)(ws + A2_OFF);
    u16*      B2t  = (u16*)(ws + B2T_OFF);
    u16*      H    = (u16*)(ws + H_OFF);
    u16*      B1t  = (u16*)(ws + B1T_OFF);
    float*    aS   = (float*)(ws + AS_OFF);
    float*    aD   = (float*)(ws + AD_OFF);
    int*      deg  = (int*)(ws + DEG_OFF);
    int*      offp = (int*)(ws + OFF_OFF);
    int*      cur  = (int*)(ws + CUR_OFF);
    int*      csr  = (int*)(ws + CSR_OFF);

    // prep (x->A1, W1->B1t) + fused edge-degree count
    hipMemsetAsync(deg, 0, NN * sizeof(int), stream);
    k_prep<<<5273, 256, 0, stream>>>(x, (uint2*)A1, W1, B1t, ei, deg);
    k_scan<<<1, 1024, 0, stream>>>(deg, offp, cur);

    // layer 1
    k_gemm<<<NWG2, 512, 0, stream>>>(A1, B1t, H, K1PAD, K1PAD / 64);
    // fused: W2->B2t + CSR scatter + layer-1 attention coefficients
    k_scatW2<<<4765, 256, 0, stream>>>(W2, B2t, ei, cur, csr, H, as1, ad1, aS, aD);
    k_agg<1><<<6536, 256, 0, stream>>>(H, aS, aD, offp, csr, b1, A2);

    // layer 2 (A2 node-major -> same contiguous-K path as gemm1)
    k_gemm<<<NWG2, 512, 0, stream>>>((u16*)A2, B2t, H, NH, NH / 64);
    k_attn<<<2500, 256, 0, stream>>>(H, as2, ad2, aS, aD);
    k_agg<2><<<6256, 256, 0, stream>>>(H, aS, aD, offp, csr, b2, A2);
    k_final<<<(NN * 64 + 255) / 256, 256, 0, stream>>>(A2, b2, (float*)d_out);
}